// Round 1
// baseline (11239.207 us; speedup 1.0000x reference)
//
#include <hip/hip_runtime.h>
#include <cstdint>

#define EPS_BN 1e-5f

// ---------------------------------------------------------------------------
// Inverted-map sparse conv encoder:
//   stage 1: y[o]   = relu(bn( sum_k feat[invd[k][o]] @ w_down[k] ))   (16 offsets, C 32->64)
//   stage 2: out[o] = relu(bn( sum_k y[invr[k][o]]   @ w_ref[k]  ))   (81 offsets, C 64->64)
// Within each offset k the scatter indices are unique, so invT[k][o] is
// conflict-free to build and the compute is atomic-free, output-coalesced.
// ---------------------------------------------------------------------------

// init: invr default = n_down (pad row of y_act, kept zero); invd default = n_in (sentinel);
// zero the y_act pad row.
__global__ void init_misc(int* __restrict__ invd, int* __restrict__ invr,
                          float* __restrict__ ypad, int n_down, int n_in) {
    long i = (long)blockIdx.x * blockDim.x + threadIdx.x;
    long nr = 81L * n_down;
    long nd = 16L * n_down;
    if (i < nr) invr[i] = n_down;
    if (i < nd) invd[i] = n_in;
    if (i < 64) ypad[i] = 0.f;
}

// scatter-build the transposed inverted map: invT[k*n_down + s] = g
__global__ void build_inv(const int* __restrict__ gather, const int* __restrict__ scatter,
                          long total, int m, int* __restrict__ invT, int n_down) {
    long i = (long)blockIdx.x * blockDim.x + threadIdx.x;
    if (i >= total) return;
    int s = scatter[i];
    if (s < n_down) {                 // skips dummy entries (s == n_down)
        int k = (int)(i / m);
        invT[(long)k * n_down + s] = gather[i];
    }
}

// Stage 1: one wave owns 16 output rows x 64 cols. lane = output column.
// Hit density ~9% -> wave-uniform per-row skip.
__global__ __launch_bounds__(256) void conv_down(
        const float* __restrict__ feat, const float* __restrict__ w,
        const int* __restrict__ invT,
        const float* __restrict__ gamma, const float* __restrict__ beta,
        const float* __restrict__ mean, const float* __restrict__ var,
        float* __restrict__ y, int n_down, int n_in) {
    int wid  = (int)(((long)blockIdx.x * blockDim.x + threadIdx.x) >> 6);
    int lane = threadIdx.x & 63;
    int o0   = wid << 4;
    if (o0 >= n_down) return;

    float acc[16];
#pragma unroll
    for (int r = 0; r < 16; ++r) acc[r] = 0.f;

    for (int k = 0; k < 16; ++k) {
        int g = n_in;
        if (lane < 16 && (o0 + lane) < n_down)
            g = invT[(long)k * n_down + o0 + lane];
#pragma unroll
        for (int r = 0; r < 16; ++r) {
            int gr = __shfl(g, r);          // wave-uniform
            if (gr >= n_in) continue;       // miss / tail row: contributes 0
            const float4* fr = (const float4*)(feat + (long)gr * 32);
            const float*  wk = w + k * 2048 + lane;
#pragma unroll
            for (int c4 = 0; c4 < 8; ++c4) {
                float4 f = fr[c4];          // wave-uniform broadcast load
                acc[r] = fmaf(f.x, wk[(c4 * 4 + 0) * 64], acc[r]);
                acc[r] = fmaf(f.y, wk[(c4 * 4 + 1) * 64], acc[r]);
                acc[r] = fmaf(f.z, wk[(c4 * 4 + 2) * 64], acc[r]);
                acc[r] = fmaf(f.w, wk[(c4 * 4 + 3) * 64], acc[r]);
            }
        }
    }

    float iv = gamma[lane] * rsqrtf(var[lane] + EPS_BN);
    float bb = beta[lane] - mean[lane] * iv;
#pragma unroll
    for (int r = 0; r < 16; ++r) {
        int o = o0 + r;
        if (o < n_down)
            y[(long)o * 64 + lane] = fmaxf(acc[r] * iv + bb, 0.f);
    }
}

// Stage 2: same tiling, 81 offsets, C 64->64. Misses read the zero pad row
// (hot in L1) instead of branching: 16 uniform float4 loads + 64 FMA per 4-col step.
__global__ __launch_bounds__(256) void conv_ref(
        const float* __restrict__ y, const float* __restrict__ w,
        const int* __restrict__ invT,
        const float* __restrict__ gamma, const float* __restrict__ beta,
        const float* __restrict__ mean, const float* __restrict__ var,
        float* __restrict__ out, int n_down) {
    int wid  = (int)(((long)blockIdx.x * blockDim.x + threadIdx.x) >> 6);
    int lane = threadIdx.x & 63;
    int o0   = wid << 4;
    if (o0 >= n_down) return;

    float acc[16];
#pragma unroll
    for (int r = 0; r < 16; ++r) acc[r] = 0.f;

    for (int k = 0; k < 81; ++k) {
        int g = n_down;                    // pad row (zeros)
        if (lane < 16 && (o0 + lane) < n_down)
            g = invT[(long)k * n_down + o0 + lane];

        const float4* yr[16];
#pragma unroll
        for (int r = 0; r < 16; ++r) {
            int gr = __shfl(g, r);
            yr[r] = (const float4*)(y + (long)gr * 64);
        }

        const float* wk = w + k * 4096 + lane;
#pragma unroll 2
        for (int c4 = 0; c4 < 16; ++c4) {
            float wv0 = wk[(c4 * 4 + 0) * 64];   // coalesced across lanes
            float wv1 = wk[(c4 * 4 + 1) * 64];
            float wv2 = wk[(c4 * 4 + 2) * 64];
            float wv3 = wk[(c4 * 4 + 3) * 64];
#pragma unroll
            for (int r = 0; r < 16; ++r) {
                float4 f = yr[r][c4];            // wave-uniform broadcast load
                acc[r] = fmaf(f.x, wv0, acc[r]);
                acc[r] = fmaf(f.y, wv1, acc[r]);
                acc[r] = fmaf(f.z, wv2, acc[r]);
                acc[r] = fmaf(f.w, wv3, acc[r]);
            }
        }
    }

    float iv = gamma[lane] * rsqrtf(var[lane] + EPS_BN);
    float bb = beta[lane] - mean[lane] * iv;
#pragma unroll
    for (int r = 0; r < 16; ++r) {
        int o = o0 + r;
        if (o < n_down)
            out[(long)o * 64 + lane] = fmaxf(acc[r] * iv + bb, 0.f);
    }
}

extern "C" void kernel_launch(void* const* d_in, const int* in_sizes, int n_args,
                              void* d_out, int out_size, void* d_ws, size_t ws_size,
                              hipStream_t stream) {
    const float* feat    = (const float*)d_in[0];
    const float* w_down  = (const float*)d_in[1];
    const float* gamma_d = (const float*)d_in[2];
    const float* beta_d  = (const float*)d_in[3];
    const float* mean_d  = (const float*)d_in[4];
    const float* var_d   = (const float*)d_in[5];
    const float* w_ref   = (const float*)d_in[6];
    const float* gamma_r = (const float*)d_in[7];
    const float* beta_r  = (const float*)d_in[8];
    const float* mean_r  = (const float*)d_in[9];
    const float* var_r   = (const float*)d_in[10];
    const int*   gather_d  = (const int*)d_in[11];
    const int*   scatter_d = (const int*)d_in[12];
    const int*   gather_r  = (const int*)d_in[13];
    const int*   scatter_r = (const int*)d_in[14];

    int n_in   = in_sizes[0] / 32;
    int md     = in_sizes[11] / 16;
    int mr     = in_sizes[13] / 81;
    int n_down = out_size / 64;     // avoids reading the scalar input's dtype

    // workspace layout: y_act[(n_down+1) x 64] f32 | invr[81 x n_down] i32 | invd[16 x n_down] i32
    float* y_act = (float*)d_ws;
    int*   invr  = (int*)((char*)d_ws + (size_t)(n_down + 1) * 64 * sizeof(float));
    int*   invd  = invr + (size_t)81 * n_down;
    float* ypad  = y_act + (size_t)n_down * 64;

    long initN = 81L * n_down;
    init_misc<<<(int)((initN + 255) / 256), 256, 0, stream>>>(invd, invr, ypad, n_down, n_in);

    long td = 16L * md;
    build_inv<<<(int)((td + 255) / 256), 256, 0, stream>>>(gather_d, scatter_d, td, md, invd, n_down);
    long tr = 81L * mr;
    build_inv<<<(int)((tr + 255) / 256), 256, 0, stream>>>(gather_r, scatter_r, tr, mr, invr, n_down);

    long waves = (n_down + 15) / 16;
    long thr   = waves * 64;
    int  blocks = (int)((thr + 255) / 256);
    conv_down<<<blocks, 256, 0, stream>>>(feat, w_down, invd,
                                          gamma_d, beta_d, mean_d, var_d,
                                          y_act, n_down, n_in);
    conv_ref<<<blocks, 256, 0, stream>>>(y_act, w_ref, invr,
                                         gamma_r, beta_r, mean_r, var_r,
                                         (float*)d_out, n_down);
}

// Round 2
// 667.476 us; speedup vs baseline: 16.8384x; 16.8384x over previous
//
#include <hip/hip_runtime.h>
#include <hip/hip_bf16.h>
#include <cstdint>

#define EPS_BN 1e-5f

typedef __attribute__((ext_vector_type(8)))  short bf16x8;   // 8 bf16 = 4 VGPRs
typedef __attribute__((ext_vector_type(16))) float f32x16;   // MFMA 32x32 accumulator

// async global->LDS, 16B per lane, dst = wave-uniform base + lane*16
#define GLOAD_LDS16(gsrc, ldst) \
    __builtin_amdgcn_global_load_lds((const __attribute__((address_space(1))) void*)(gsrc), \
                                     (__attribute__((address_space(3))) void*)(ldst), 16, 0, 0)

// ---------------------------------------------------------------------------
// init: invr default = n_down (pad row of y, kept zero); invd default = n_in
// (sentinel, stage-1 skips); zero the bf16 y pad row.
// ---------------------------------------------------------------------------
__global__ void init_misc(int* __restrict__ invd, int* __restrict__ invr,
                          unsigned short* __restrict__ ypad, int n_down, int n_in) {
    long i = (long)blockIdx.x * blockDim.x + threadIdx.x;
    if (i < 81L * n_down) invr[i] = n_down;
    if (i < 16L * n_down) invd[i] = n_in;
    if (i < 64) ypad[i] = 0;
}

// scatter-build transposed inverted map: invT[k*n_down + s] = g  (s unique per k)
__global__ void build_inv(const int* __restrict__ gather, const int* __restrict__ scatter,
                          long total, int m, int* __restrict__ invT, int n_down) {
    long i = (long)blockIdx.x * blockDim.x + threadIdx.x;
    if (i >= total) return;
    int s = scatter[i];
    if (s < n_down) {
        int k = (int)(i / m);
        invT[(long)k * n_down + s] = gather[i];
    }
}

// ---------------------------------------------------------------------------
// Convert w_ref f32[81][64cin][64cout] -> bf16, TRANSPOSED to [81][col][kk] and
// XOR-swizzled (byte ^= (col&7)<<4 within each 128B row) so that a LINEAR
// global_load_lds stage yields the swizzled LDS layout directly (both-sides rule).
// ---------------------------------------------------------------------------
__global__ void wcvt(const float* __restrict__ w, unsigned short* __restrict__ wt) {
    int e = blockIdx.x * 256 + threadIdx.x;          // 81*4096 elements
    int k = e >> 12;
    int r = e & 4095;
    int col = r >> 6;                                // 0..63 (cout)
    int b   = (r & 63) << 1;                         // byte offset within row
    int kk  = (b ^ ((col & 7) << 4)) >> 1;           // swizzled cin index
    float v = w[(k << 12) + (kk << 6) + col];
    __hip_bfloat16 h = __float2bfloat16(v);
    wt[e] = *(unsigned short*)&h;
}

// ---------------------------------------------------------------------------
// Stage 1 (small: ~1.6 GFLOP, ~9% hit density): f32 VALU, one wave = 16 rows
// x 64 cols, wave-uniform per-row skip. Output stored as bf16 (+ BN + ReLU).
// ---------------------------------------------------------------------------
__global__ __launch_bounds__(256) void conv_down(
        const float* __restrict__ feat, const float* __restrict__ w,
        const int* __restrict__ invT,
        const float* __restrict__ gamma, const float* __restrict__ beta,
        const float* __restrict__ mean, const float* __restrict__ var,
        unsigned short* __restrict__ y, int n_down, int n_in) {
    int wid  = (int)(((long)blockIdx.x * blockDim.x + threadIdx.x) >> 6);
    int lane = threadIdx.x & 63;
    int o0   = wid << 4;
    if (o0 >= n_down) return;

    float acc[16];
#pragma unroll
    for (int r = 0; r < 16; ++r) acc[r] = 0.f;

    for (int k = 0; k < 16; ++k) {
        int g = n_in;
        if (lane < 16 && (o0 + lane) < n_down)
            g = invT[(long)k * n_down + o0 + lane];
#pragma unroll
        for (int r = 0; r < 16; ++r) {
            int gr = __shfl(g, r);
            if (gr >= n_in) continue;
            const float4* fr = (const float4*)(feat + (long)gr * 32);
            const float*  wk = w + k * 2048 + lane;
#pragma unroll
            for (int c4 = 0; c4 < 8; ++c4) {
                float4 f = fr[c4];
                acc[r] = fmaf(f.x, wk[(c4 * 4 + 0) * 64], acc[r]);
                acc[r] = fmaf(f.y, wk[(c4 * 4 + 1) * 64], acc[r]);
                acc[r] = fmaf(f.z, wk[(c4 * 4 + 2) * 64], acc[r]);
                acc[r] = fmaf(f.w, wk[(c4 * 4 + 3) * 64], acc[r]);
            }
        }
    }

    float iv = gamma[lane] * rsqrtf(var[lane] + EPS_BN);
    float bb = beta[lane] - mean[lane] * iv;
#pragma unroll
    for (int r = 0; r < 16; ++r) {
        int o = o0 + r;
        if (o < n_down) {
            __hip_bfloat16 h = __float2bfloat16(fmaxf(acc[r] * iv + bb, 0.f));
            y[(long)o * 64 + lane] = *(unsigned short*)&h;
        }
    }
}

// ---------------------------------------------------------------------------
// Stage 2 (dominant: ~101 GFLOP): MFMA bf16. Block = 4 waves x 32 rows = 128
// output rows. Per k-offset: gather 32 y-rows as the A operand
// (mfma_f32_32x32x16_bf16: A row = lane%32, k = (lane/32)*8+j), W[k] staged
// once per block in double-buffered LDS as the B operand (col = lane%32,
// k = (lane/32)*8+j), acc = 2 n-tiles of 32x32 f32.
// C/D layout (m74-verified): col = lane&31, row = (reg&3)+8*(reg>>2)+4*(lane>>5).
// ---------------------------------------------------------------------------
__global__ __launch_bounds__(256) void conv_ref_mfma(
        const unsigned short* __restrict__ ybf, const unsigned short* __restrict__ wt,
        const int* __restrict__ invr,
        const float* __restrict__ gamma, const float* __restrict__ beta,
        const float* __restrict__ mean, const float* __restrict__ var,
        float* __restrict__ out, int n_down) {
    __shared__ char Wlds[2][8192];

    const int tid  = threadIdx.x;
    const int lane = tid & 63;
    const int wid  = tid >> 6;
    const int l31  = lane & 31;
    const int lhi  = lane >> 5;                       // 0/1
    const long o0w = (long)blockIdx.x * 128 + wid * 32;
    const int  o   = (int)(o0w + l31);
    const bool valid = (o0w + l31) < n_down;

    const short* ys   = (const short*)ybf;
    const char*  wt_b = (const char*)wt;

    // loop-invariant swizzled LDS byte offsets for the 8 B-fragments
    int boff[2][4];
#pragma unroll
    for (int n = 0; n < 2; ++n)
#pragma unroll
        for (int kq = 0; kq < 4; ++kq)
            boff[n][kq] = (n * 32 + l31) * 128 + ((kq * 32 + lhi * 16) ^ ((lane & 7) << 4));

    f32x16 acc[2] = {};

    // prologue: stage W[0] into buffer 0 (each wave copies 2 x 1024B)
    {
        const char* src = wt_b + wid * 1024;
#pragma unroll
        for (int c = 0; c < 2; ++c)
            GLOAD_LDS16(src + c * 4096 + lane * 16, &Wlds[0][wid * 1024 + c * 4096]);
    }

    for (int k = 0; k < 81; ++k) {
        const int cur = k & 1;
        __syncthreads();                              // W[k] staged; buf[cur^1] free
        if (k < 80) {                                 // stage W[k+1] (async across compute)
            const char* src = wt_b + (size_t)(k + 1) * 8192 + wid * 1024;
#pragma unroll
            for (int c = 0; c < 2; ++c)
                GLOAD_LDS16(src + c * 4096 + lane * 16, &Wlds[cur ^ 1][wid * 1024 + c * 4096]);
        }

        int g = n_down;                               // pad row (zeros)
        if (valid) g = invr[(size_t)k * n_down + o];

        const short* arow = ys + (size_t)g * 64 + lhi * 8;
        bf16x8 a[4];
#pragma unroll
        for (int kq = 0; kq < 4; ++kq)
            a[kq] = *(const bf16x8*)(arow + kq * 16);

#pragma unroll
        for (int kq = 0; kq < 4; ++kq) {
            bf16x8 b0 = *(const bf16x8*)(&Wlds[cur][boff[0][kq]]);
            bf16x8 b1 = *(const bf16x8*)(&Wlds[cur][boff[1][kq]]);
            acc[0] = __builtin_amdgcn_mfma_f32_32x32x16_bf16(a[kq], b0, acc[0], 0, 0, 0);
            acc[1] = __builtin_amdgcn_mfma_f32_32x32x16_bf16(a[kq], b1, acc[1], 0, 0, 0);
        }
    }

    // epilogue: BN + ReLU, f32 out
#pragma unroll
    for (int n = 0; n < 2; ++n) {
        int col = n * 32 + l31;
        float iv = gamma[col] * rsqrtf(var[col] + EPS_BN);
        float bb = beta[col] - mean[col] * iv;
#pragma unroll
        for (int i = 0; i < 16; ++i) {
            int row = (i & 3) + 8 * (i >> 2) + 4 * lhi;
            long oo = o0w + row;
            if (oo < n_down)
                out[oo * 64 + col] = fmaxf(acc[n][i] * iv + bb, 0.f);
        }
    }
}

extern "C" void kernel_launch(void* const* d_in, const int* in_sizes, int n_args,
                              void* d_out, int out_size, void* d_ws, size_t ws_size,
                              hipStream_t stream) {
    const float* feat    = (const float*)d_in[0];
    const float* w_down  = (const float*)d_in[1];
    const float* gamma_d = (const float*)d_in[2];
    const float* beta_d  = (const float*)d_in[3];
    const float* mean_d  = (const float*)d_in[4];
    const float* var_d   = (const float*)d_in[5];
    const float* w_ref   = (const float*)d_in[6];
    const float* gamma_r = (const float*)d_in[7];
    const float* beta_r  = (const float*)d_in[8];
    const float* mean_r  = (const float*)d_in[9];
    const float* var_r   = (const float*)d_in[10];
    const int*   gather_d  = (const int*)d_in[11];
    const int*   scatter_d = (const int*)d_in[12];
    const int*   gather_r  = (const int*)d_in[13];
    const int*   scatter_r = (const int*)d_in[14];

    int n_in   = in_sizes[0] / 32;
    int md     = in_sizes[11] / 16;
    int mr     = in_sizes[13] / 81;
    int n_down = out_size / 64;

    // ws layout: y_bf16[(n_down+1)*64] | wt_bf16[81*4096] (256B aligned) | invr | invd
    char* ws = (char*)d_ws;
    size_t off = 0;
    unsigned short* ybf = (unsigned short*)(ws + off);
    off += (size_t)(n_down + 1) * 64 * sizeof(unsigned short);
    off = (off + 255) & ~(size_t)255;
    unsigned short* wt = (unsigned short*)(ws + off);
    off += (size_t)81 * 4096 * sizeof(unsigned short);
    int* invr = (int*)(ws + off);
    off += (size_t)81 * n_down * sizeof(int);
    int* invd = (int*)(ws + off);

    long initN = 81L * n_down;
    init_misc<<<(int)((initN + 255) / 256), 256, 0, stream>>>(
        invd, invr, ybf + (size_t)n_down * 64, n_down, n_in);

    long td = 16L * md;
    build_inv<<<(int)((td + 255) / 256), 256, 0, stream>>>(gather_d, scatter_d, td, md, invd, n_down);
    long tr = 81L * mr;
    build_inv<<<(int)((tr + 255) / 256), 256, 0, stream>>>(gather_r, scatter_r, tr, mr, invr, n_down);

    wcvt<<<81 * 4096 / 256, 256, 0, stream>>>(w_ref, wt);

    long waves = (n_down + 15) / 16;
    long thr   = waves * 64;
    conv_down<<<(int)((thr + 255) / 256), 256, 0, stream>>>(
        feat, w_down, invd, gamma_d, beta_d, mean_d, var_d, ybf, n_down, n_in);

    int blocks2 = (n_down + 127) / 128;
    conv_ref_mfma<<<blocks2, 256, 0, stream>>>(
        ybf, wt, invr, gamma_r, beta_r, mean_r, var_r, (float*)d_out, n_down);
}

// Round 3
// 571.560 us; speedup vs baseline: 19.6641x; 1.1678x over previous
//
#include <hip/hip_runtime.h>
#include <hip/hip_bf16.h>
#include <cstdint>

#define EPS_BN 1e-5f

typedef __attribute__((ext_vector_type(8)))  short bf16x8;   // 8 bf16 = 4 VGPRs
typedef __attribute__((ext_vector_type(16))) float f32x16;   // MFMA 32x32 acc
typedef __attribute__((ext_vector_type(4)))  unsigned short u16x4;

#define MFMA32(a, b, c) __builtin_amdgcn_mfma_f32_32x32x16_bf16(a, b, c, 0, 0, 0)

// ---------------------------------------------------------------------------
// build transposed inverted map: invT[k*n_down + s] = g  (s unique per k).
// Table pre-memset to 0xFF (-1 = miss).
// ---------------------------------------------------------------------------
__global__ void build_inv(const int* __restrict__ gather, const int* __restrict__ scatter,
                          long total, int m, int* __restrict__ invT, int n_down) {
    long i = (long)blockIdx.x * blockDim.x + threadIdx.x;
    if (i >= total) return;
    int s = scatter[i];
    if (s < n_down) {
        int k = (int)(i / m);
        invT[(long)k * n_down + s] = gather[i];
    }
}

// feat f32[n_in][32] -> bf16 [n_in+1][32] (pad row zero); also zero ybf pad row.
__global__ void fcvt(const float* __restrict__ f, unsigned short* __restrict__ fb,
                     unsigned short* __restrict__ ybf_pad, long n_in) {
    long t = (long)blockIdx.x * blockDim.x + threadIdx.x;
    long e = t * 4;
    long total = n_in * 32;
    if (e < total) {
        float4 v = *(const float4*)(f + e);
        u16x4 o;
        __hip_bfloat16 h;
        h = __float2bfloat16(v.x); o.x = *(unsigned short*)&h;
        h = __float2bfloat16(v.y); o.y = *(unsigned short*)&h;
        h = __float2bfloat16(v.z); o.z = *(unsigned short*)&h;
        h = __float2bfloat16(v.w); o.w = *(unsigned short*)&h;
        *(u16x4*)(fb + e) = o;
    } else if (e < total + 32) {
        u16x4 z = {0, 0, 0, 0};
        *(u16x4*)(fb + e) = z;
    }
    if (blockIdx.x == 0 && threadIdx.x < 16) {
        u16x4 z = {0, 0, 0, 0};
        ((u16x4*)ybf_pad)[threadIdx.x] = z;
    }
}

// w_ref f32[81][64cin][64cout] -> bf16 wt[k][kq(4)][col(64)][16] where slot
// (col, lhi*8+j) of kq holds w[cin = kq*16+lhi*8+j][col].  Lane-fragment load
// becomes one coalesced b128 per (kq, ntile).
__global__ void wcvt_r(const float* __restrict__ w, unsigned short* __restrict__ wt) {
    int e = blockIdx.x * 256 + threadIdx.x;      // 81*4096
    int k = e >> 12, r = e & 4095;
    int cin = ((r >> 10) << 4) + (r & 15);
    int col = (r >> 4) & 63;
    __hip_bfloat16 h = __float2bfloat16(w[(k << 12) + (cin << 6) + col]);
    wt[e] = *(unsigned short*)&h;
}

// w_down f32[16][32cin][64cout] -> bf16 wtd[k][kq(2)][col(64)][16]
__global__ void wcvt_d(const float* __restrict__ w, unsigned short* __restrict__ wt) {
    int e = blockIdx.x * 256 + threadIdx.x;      // 16*2048
    int k = e >> 11, r = e & 2047;
    int cin = ((r >> 10) << 4) + (r & 15);
    int col = (r >> 4) & 63;
    __hip_bfloat16 h = __float2bfloat16(w[(k << 11) + (cin << 6) + col]);
    wt[e] = *(unsigned short*)&h;
}

// ---------------------------------------------------------------------------
// Stage 1: MFMA bf16, K=32 (2 kq steps), one wave = 32 rows x 64 cols.
// 91% of A-rows are the pad row (L1-hot). idx prefetch dist 3, A dist 1.
// ---------------------------------------------------------------------------
__global__ __launch_bounds__(256, 4) void conv_down_mfma(
        const unsigned short* __restrict__ fb, const unsigned short* __restrict__ wtd,
        const int* __restrict__ invd,
        const float* __restrict__ gamma, const float* __restrict__ beta,
        const float* __restrict__ mean, const float* __restrict__ var,
        unsigned short* __restrict__ y, int n_down, int n_in) {
    int  tid  = threadIdx.x;
    int  lane = tid & 63, l31 = lane & 31, lhi = lane >> 5;
    long wv   = ((long)blockIdx.x * 256 + tid) >> 6;
    long o0   = wv * 32;
    if (o0 >= n_down) return;

    int  oA = (int)(o0 + l31 < n_down ? o0 + l31 : n_down - 1);
    bool vA = (o0 + l31) < n_down;
    const short* ysb = (const short*)fb;

#define LDI_D(k) (vA ? invd[(size_t)(k) * n_down + oA] : -1)
#define GATH_D(dst, g) { \
        const short* p = ysb + (size_t)((g) < 0 ? n_in : (g)) * 32 + lhi * 8; \
        dst[0] = *(const bf16x8*)p; dst[1] = *(const bf16x8*)(p + 16); }

    int g0 = LDI_D(0), gq1 = LDI_D(1), gq2 = LDI_D(2);
    bf16x8 ac[2];
    GATH_D(ac, g0);
    f32x16 acc0 = {}, acc1 = {};
    const short* wp = (const short*)wtd + l31 * 16 + lhi * 8;

    for (int k = 0; k < 16; ++k) {
        int gN = (k < 13) ? LDI_D(k + 3) : -1;
        bf16x8 an[2];
        GATH_D(an, gq1);
        const short* wk = wp + k * 2048;
#pragma unroll
        for (int kq = 0; kq < 2; ++kq) {
            bf16x8 b0 = *(const bf16x8*)(wk + kq * 1024);
            bf16x8 b1 = *(const bf16x8*)(wk + kq * 1024 + 512);
            acc0 = MFMA32(ac[kq], b0, acc0);
            acc1 = MFMA32(ac[kq], b1, acc1);
        }
        ac[0] = an[0]; ac[1] = an[1];
        gq1 = gq2; gq2 = gN;
    }

#pragma unroll
    for (int n = 0; n < 2; ++n) {
        int col = n * 32 + l31;
        float iv = gamma[col] * rsqrtf(var[col] + EPS_BN);
        float bb = beta[col] - mean[col] * iv;
        const f32x16& A = n ? acc1 : acc0;
#pragma unroll
        for (int i = 0; i < 16; ++i) {
            long oo = o0 + (i & 3) + 8 * (i >> 2) + 4 * lhi;
            if (oo < n_down) {
                __hip_bfloat16 h = __float2bfloat16(fmaxf(A[i] * iv + bb, 0.f));
                y[oo * 64 + col] = *(unsigned short*)&h;
            }
        }
    }
#undef LDI_D
#undef GATH_D
}

// ---------------------------------------------------------------------------
// Stage 2: MFMA bf16, K=64 (4 kq), one wave = 64 rows (2 row-tiles) x 64 cols.
// No LDS, no barriers: B streamed global->reg (L1/L2-hot), A gathered with
// source-level pipeline (idx dist 3 covers HBM stream, A dist 1 covers L3).
// XCD-bijective block swizzle for gather L2 locality.
// ---------------------------------------------------------------------------
__global__ __launch_bounds__(256, 3) void conv_ref_mfma(
        const unsigned short* __restrict__ ybf, const unsigned short* __restrict__ wt,
        const int* __restrict__ invr,
        const float* __restrict__ gamma, const float* __restrict__ beta,
        const float* __restrict__ mean, const float* __restrict__ var,
        float* __restrict__ out, int n_down, int nwg) {
    // bijective XCD swizzle (m204 variant)
    int bid = blockIdx.x;
    int q = nwg >> 3, r = nwg & 7;
    int xcd = bid & 7, pos = bid >> 3;
    int swz = (xcd < r ? xcd * (q + 1) : r * (q + 1) + (xcd - r) * q) + pos;

    int  tid  = threadIdx.x;
    int  lane = tid & 63, l31 = lane & 31, lhi = lane >> 5;
    long wv   = (long)swz * 4 + (tid >> 6);
    long o0   = wv * 64;
    if (o0 >= n_down) return;

    int  oA = (int)(o0 + l31 < n_down ? o0 + l31 : n_down - 1);
    int  oB = (int)(o0 + 32 + l31 < n_down ? o0 + 32 + l31 : n_down - 1);
    bool vA = (o0 + l31) < n_down, vB = (o0 + 32 + l31) < n_down;
    const short* ysb = (const short*)ybf;

#define LDI_R(k, ga, gb) { \
        const int* p = invr + (size_t)(k) * n_down; \
        ga = vA ? p[oA] : -1; gb = vB ? p[oB] : -1; }
#define GATH_R(dst, ga, gb) { \
        const short* pa = ysb + (size_t)((ga) < 0 ? n_down : (ga)) * 64 + lhi * 8; \
        const short* pb = ysb + (size_t)((gb) < 0 ? n_down : (gb)) * 64 + lhi * 8; \
        _Pragma("unroll") \
        for (int kq = 0; kq < 4; ++kq) { \
            dst[kq]     = *(const bf16x8*)(pa + kq * 16); \
            dst[4 + kq] = *(const bf16x8*)(pb + kq * 16); } }

    int g0a, g0b, g1a, g1b, g2a, g2b;
    LDI_R(0, g0a, g0b);
    LDI_R(1, g1a, g1b);
    LDI_R(2, g2a, g2b);
    bf16x8 ac[8];
    GATH_R(ac, g0a, g0b);
    f32x16 acc0 = {}, acc1 = {}, acc2 = {}, acc3 = {};
    const short* wp = (const short*)wt + l31 * 16 + lhi * 8;

    for (int k = 0; k < 81; ++k) {
        int gNa = -1, gNb = -1;
        if (k < 78) LDI_R(k + 3, gNa, gNb);
        bf16x8 an[8];
        GATH_R(an, g1a, g1b);
        const short* wk = wp + k * 4096;
#pragma unroll
        for (int kq = 0; kq < 4; ++kq) {
            bf16x8 b0 = *(const bf16x8*)(wk + kq * 1024);
            bf16x8 b1 = *(const bf16x8*)(wk + kq * 1024 + 512);
            acc0 = MFMA32(ac[kq],     b0, acc0);
            acc1 = MFMA32(ac[kq],     b1, acc1);
            acc2 = MFMA32(ac[4 + kq], b0, acc2);
            acc3 = MFMA32(ac[4 + kq], b1, acc3);
        }
#pragma unroll
        for (int i = 0; i < 8; ++i) ac[i] = an[i];
        g1a = g2a; g1b = g2b; g2a = gNa; g2b = gNb;
    }

#pragma unroll
    for (int m = 0; m < 2; ++m)
#pragma unroll
        for (int n = 0; n < 2; ++n) {
            int col = n * 32 + l31;
            float iv = gamma[col] * rsqrtf(var[col] + EPS_BN);
            float bb = beta[col] - mean[col] * iv;
            const f32x16& A = m == 0 ? (n == 0 ? acc0 : acc1) : (n == 0 ? acc2 : acc3);
#pragma unroll
            for (int i = 0; i < 16; ++i) {
                long oo = o0 + m * 32 + (i & 3) + 8 * (i >> 2) + 4 * lhi;
                if (oo < n_down)
                    out[oo * 64 + col] = fmaxf(A[i] * iv + bb, 0.f);
            }
        }
#undef LDI_R
#undef GATH_R
}

extern "C" void kernel_launch(void* const* d_in, const int* in_sizes, int n_args,
                              void* d_out, int out_size, void* d_ws, size_t ws_size,
                              hipStream_t stream) {
    const float* feat    = (const float*)d_in[0];
    const float* w_down  = (const float*)d_in[1];
    const float* gamma_d = (const float*)d_in[2];
    const float* beta_d  = (const float*)d_in[3];
    const float* mean_d  = (const float*)d_in[4];
    const float* var_d   = (const float*)d_in[5];
    const float* w_ref   = (const float*)d_in[6];
    const float* gamma_r = (const float*)d_in[7];
    const float* beta_r  = (const float*)d_in[8];
    const float* mean_r  = (const float*)d_in[9];
    const float* var_r   = (const float*)d_in[10];
    const int*   gather_d  = (const int*)d_in[11];
    const int*   scatter_d = (const int*)d_in[12];
    const int*   gather_r  = (const int*)d_in[13];
    const int*   scatter_r = (const int*)d_in[14];

    int n_in   = in_sizes[0] / 32;
    int md     = in_sizes[11] / 16;
    int mr     = in_sizes[13] / 81;
    int n_down = out_size / 64;

    // ws: ybf[(n_down+1)*64]bf16 | featbf[(n_in+1)*32]bf16 | wt[81*4096]bf16 |
    //     wtd[16*2048]bf16 | invr[81*n_down]i32 | invd[16*n_down]i32 (contig for memset)
    char* ws = (char*)d_ws;
    size_t off = 0;
    auto alloc = [&](size_t bytes) { char* p = ws + off; off = (off + bytes + 255) & ~(size_t)255; return p; };
    unsigned short* ybf    = (unsigned short*)alloc((size_t)(n_down + 1) * 64 * 2);
    unsigned short* featbf = (unsigned short*)alloc((size_t)(n_in + 1) * 32 * 2);
    unsigned short* wt     = (unsigned short*)alloc((size_t)81 * 4096 * 2);
    unsigned short* wtd    = (unsigned short*)alloc((size_t)16 * 2048 * 2);
    int* invr = (int*)(ws + off);
    int* invd = invr + (size_t)81 * n_down;

    hipMemsetAsync(invr, 0xFF, (size_t)97 * n_down * sizeof(int), stream);

    long td = 16L * md;
    build_inv<<<(int)((td + 255) / 256), 256, 0, stream>>>(gather_d, scatter_d, td, md, invd, n_down);
    long tr = 81L * mr;
    build_inv<<<(int)((tr + 255) / 256), 256, 0, stream>>>(gather_r, scatter_r, tr, mr, invr, n_down);

    long ft = ((long)n_in * 32 + 32) / 4;
    fcvt<<<(int)((ft + 255) / 256), 256, 0, stream>>>(feat, featbf, ybf + (size_t)n_down * 64, n_in);
    wcvt_r<<<81 * 4096 / 256, 256, 0, stream>>>(w_ref, wt);
    wcvt_d<<<16 * 2048 / 256, 256, 0, stream>>>(w_down, wtd);

    long wavesD  = ((long)n_down + 31) / 32;
    int  blocksD = (int)((wavesD * 64 + 255) / 256);
    conv_down_mfma<<<blocksD, 256, 0, stream>>>(featbf, wtd, invd,
                                                gamma_d, beta_d, mean_d, var_d,
                                                ybf, n_down, n_in);

    long wavesR  = ((long)n_down + 63) / 64;
    int  blocksR = (int)((wavesR + 3) / 4);
    conv_ref_mfma<<<blocksR, 256, 0, stream>>>(ybf, wt, invr,
                                               gamma_r, beta_r, mean_r, var_r,
                                               (float*)d_out, n_down, blocksR);
}

// Round 4
// 392.748 us; speedup vs baseline: 28.6168x; 1.4553x over previous
//
#include <hip/hip_runtime.h>
#include <hip/hip_bf16.h>
#include <cstdint>

#define EPS_BN 1e-5f

typedef __attribute__((ext_vector_type(8)))  short bf16x8;   // 8 bf16 = 4 VGPRs
typedef __attribute__((ext_vector_type(16))) float f32x16;   // MFMA 32x32 acc
typedef __attribute__((ext_vector_type(4)))  unsigned short u16x4;

#define MFMA32(a, b, c) __builtin_amdgcn_mfma_f32_32x32x16_bf16(a, b, c, 0, 0, 0)

// async global->LDS, 16B/lane: per-lane GLOBAL src, LDS dst = uniform base + lane*16
#define GLOAD_LDS16(gsrc, ldst) \
    __builtin_amdgcn_global_load_lds((const __attribute__((address_space(1))) void*)(gsrc), \
                                     (__attribute__((address_space(3))) void*)(ldst), 16, 0, 0)

// ---------------------------------------------------------------------------
// build transposed inverted map: invT[k*n_down + s] = g  (s unique per k).
// Table pre-memset to 0xFF (-1 = miss).
// ---------------------------------------------------------------------------
__global__ void build_inv(const int* __restrict__ gather, const int* __restrict__ scatter,
                          long total, int m, int* __restrict__ invT, int n_down) {
    long i = (long)blockIdx.x * blockDim.x + threadIdx.x;
    if (i >= total) return;
    int s = scatter[i];
    if (s < n_down) {
        int k = (int)(i / m);
        invT[(long)k * n_down + s] = gather[i];
    }
}

// feat f32[n_in][32] -> bf16 [n_in+1][32] (pad row zero); also zero ybf pad row.
__global__ void fcvt(const float* __restrict__ f, unsigned short* __restrict__ fb,
                     unsigned short* __restrict__ ybf_pad, long n_in) {
    long t = (long)blockIdx.x * blockDim.x + threadIdx.x;
    long e = t * 4;
    long total = n_in * 32;
    if (e < total) {
        float4 v = *(const float4*)(f + e);
        u16x4 o;
        __hip_bfloat16 h;
        h = __float2bfloat16(v.x); o.x = *(unsigned short*)&h;
        h = __float2bfloat16(v.y); o.y = *(unsigned short*)&h;
        h = __float2bfloat16(v.z); o.z = *(unsigned short*)&h;
        h = __float2bfloat16(v.w); o.w = *(unsigned short*)&h;
        *(u16x4*)(fb + e) = o;
    } else if (e < total + 32) {
        u16x4 z = {0, 0, 0, 0};
        *(u16x4*)(fb + e) = z;
    }
    if (blockIdx.x == 0 && threadIdx.x < 16) {
        u16x4 z = {0, 0, 0, 0};
        ((u16x4*)ybf_pad)[threadIdx.x] = z;
    }
}

// w_ref f32[81][64cin][64cout] -> bf16 wt[k][kq(4)][col(64)][16]: slot
// (col, lhi*8+j) of kq holds w[cin = kq*16+lhi*8+j][col] -> one coalesced b128
// per (kq, ntile) B-fragment load.
__global__ void wcvt_r(const float* __restrict__ w, unsigned short* __restrict__ wt) {
    int e = blockIdx.x * 256 + threadIdx.x;      // 81*4096
    int k = e >> 12, r = e & 4095;
    int cin = ((r >> 10) << 4) + (r & 15);
    int col = (r >> 4) & 63;
    __hip_bfloat16 h = __float2bfloat16(w[(k << 12) + (cin << 6) + col]);
    wt[e] = *(unsigned short*)&h;
}

// w_down f32[16][32cin][64cout] -> bf16 wtd[k][kq(2)][col(64)][16]
__global__ void wcvt_d(const float* __restrict__ w, unsigned short* __restrict__ wt) {
    int e = blockIdx.x * 256 + threadIdx.x;      // 16*2048
    int k = e >> 11, r = e & 2047;
    int cin = ((r >> 10) << 4) + (r & 15);
    int col = (r >> 4) & 63;
    __hip_bfloat16 h = __float2bfloat16(w[(k << 11) + (cin << 6) + col]);
    wt[e] = *(unsigned short*)&h;
}

// ---------------------------------------------------------------------------
// Stage 1: MFMA bf16, K=32, one wave = 32 rows. 91% pad-row gathers (L1-hot).
// (unchanged from R3 — not the bottleneck this round)
// ---------------------------------------------------------------------------
__global__ __launch_bounds__(256, 4) void conv_down_mfma(
        const unsigned short* __restrict__ fb, const unsigned short* __restrict__ wtd,
        const int* __restrict__ invd,
        const float* __restrict__ gamma, const float* __restrict__ beta,
        const float* __restrict__ mean, const float* __restrict__ var,
        unsigned short* __restrict__ y, int n_down, int n_in) {
    int  tid  = threadIdx.x;
    int  lane = tid & 63, l31 = lane & 31, lhi = lane >> 5;
    long wv   = ((long)blockIdx.x * 256 + tid) >> 6;
    long o0   = wv * 32;
    if (o0 >= n_down) return;

    int  oA = (int)(o0 + l31 < n_down ? o0 + l31 : n_down - 1);
    bool vA = (o0 + l31) < n_down;
    const short* ysb = (const short*)fb;

#define LDI_D(k) (vA ? invd[(size_t)(k) * n_down + oA] : -1)
#define GATH_D(dst, g) { \
        const short* p = ysb + (size_t)((g) < 0 ? n_in : (g)) * 32 + lhi * 8; \
        dst[0] = *(const bf16x8*)p; dst[1] = *(const bf16x8*)(p + 16); }

    int g0 = LDI_D(0), gq1 = LDI_D(1), gq2 = LDI_D(2);
    bf16x8 ac[2];
    GATH_D(ac, g0);
    f32x16 acc0 = {}, acc1 = {};
    const short* wp = (const short*)wtd + l31 * 16 + lhi * 8;

    for (int k = 0; k < 16; ++k) {
        int gN = (k < 13) ? LDI_D(k + 3) : -1;
        bf16x8 an[2];
        GATH_D(an, gq1);
        const short* wk = wp + k * 2048;
#pragma unroll
        for (int kq = 0; kq < 2; ++kq) {
            bf16x8 b0 = *(const bf16x8*)(wk + kq * 1024);
            bf16x8 b1 = *(const bf16x8*)(wk + kq * 1024 + 512);
            acc0 = MFMA32(ac[kq], b0, acc0);
            acc1 = MFMA32(ac[kq], b1, acc1);
        }
        ac[0] = an[0]; ac[1] = an[1];
        gq1 = gq2; gq2 = gN;
    }

#pragma unroll
    for (int n = 0; n < 2; ++n) {
        int col = n * 32 + l31;
        float iv = gamma[col] * rsqrtf(var[col] + EPS_BN);
        float bb = beta[col] - mean[col] * iv;
        const f32x16& A = n ? acc1 : acc0;
#pragma unroll
        for (int i = 0; i < 16; ++i) {
            long oo = o0 + (i & 3) + 8 * (i >> 2) + 4 * lhi;
            if (oo < n_down) {
                __hip_bfloat16 h = __float2bfloat16(fmaxf(A[i] * iv + bb, 0.f));
                y[oo * 64 + col] = *(unsigned short*)&h;
            }
        }
    }
#undef LDI_D
#undef GATH_D
}

// ---------------------------------------------------------------------------
// Stage 2: MFMA bf16, one wave = 64 rows x 64 cols, k = 81 offsets.
// A gathered into PER-WAVE double-buffered LDS via global_load_lds (per-lane
// global src, pre-swizzled; linear LDS dst). No barriers: counted
// s_waitcnt vmcnt(17) per region (= exactly this region's 8 stage + 1 idx +
// 8 B issues) drains the PREVIOUS region's stage. B global->reg, 1-deep
// prefetch into named sets. idx prefetch distance 3.
// ---------------------------------------------------------------------------
__global__ __launch_bounds__(256, 2) void conv_ref_mfma(
        const unsigned short* __restrict__ ybf, const unsigned short* __restrict__ wt,
        const int* __restrict__ invr,
        const float* __restrict__ gamma, const float* __restrict__ beta,
        const float* __restrict__ mean, const float* __restrict__ var,
        float* __restrict__ out, int n_down, int nwg) {
    __shared__ char ldsA[4][2][8192];            // [wave][buf][64 rows x 128B]

    // bijective XCD swizzle (m204)
    int bid = blockIdx.x;
    int q = nwg >> 3, r = nwg & 7;
    int xcd = bid & 7, pos = bid >> 3;
    int swzb = (xcd < r ? xcd * (q + 1) : r * (q + 1) + (xcd - r) * q) + pos;

    const int tid  = threadIdx.x;
    const int lane = tid & 63, l31 = lane & 31, lhi = lane >> 5;
    const int wid  = tid >> 6;
    const long o0  = ((long)swzb * 4 + wid) * 64;
    if (o0 >= n_down) return;

    const int oL = (int)(o0 + lane < n_down ? o0 + lane : n_down - 1);
    const char* ybase = (const char*)ybf;
    char* ldsw = &ldsA[wid][0][0];
    // source swizzle: row r=i*8+(lane>>3); col (lane&7)*16 XOR ((r&7)<<4)
    const int swz = (((lane & 7) ^ (lane >> 3)) << 4);

    // staging: instr i gathers rows i*8..i*8+7 (row = i*8 + lane/8)
#define STAGE(buf, gv) \
    _Pragma("unroll") \
    for (int i = 0; i < 8; ++i) { \
        int gi = __shfl((gv), (i << 3) + (lane >> 3)); \
        size_t grow = (gi < 0) ? (size_t)n_down : (size_t)gi; \
        GLOAD_LDS16(ybase + grow * 128 + swz, ldsw + (buf) * 8192 + i * 1024); \
    }

#define LDB(dst, k) { \
        const short* wk_ = wp + (size_t)(k) * 4096; \
        _Pragma("unroll") \
        for (int kq = 0; kq < 4; ++kq) { \
            dst##0[kq] = *(const bf16x8*)(wk_ + kq * 1024); \
            dst##1[kq] = *(const bf16x8*)(wk_ + kq * 1024 + 512); } }

    // A-fragment LDS byte offsets (loop-invariant, swizzled)
    const int rsw = (l31 & 7) << 4;
    const int f0 = (0  + lhi * 16) ^ rsw, f1 = (32 + lhi * 16) ^ rsw;
    const int f2 = (64 + lhi * 16) ^ rsw, f3 = (96 + lhi * 16) ^ rsw;
    const int rowA = l31 * 128, rowB = (32 + l31) * 128;

#define COMPUTE(buf, B) { \
        const char* lb = ldsw + (buf) * 8192; \
        _Pragma("unroll") \
        for (int kq = 0; kq < 4; ++kq) { \
            int fo = kq == 0 ? f0 : kq == 1 ? f1 : kq == 2 ? f2 : f3; \
            bf16x8 aA = *(const bf16x8*)(lb + rowA + fo); \
            bf16x8 aB = *(const bf16x8*)(lb + rowB + fo); \
            acc0 = MFMA32(aA, B##0[kq], acc0); \
            acc1 = MFMA32(aA, B##1[kq], acc1); \
            acc2 = MFMA32(aB, B##0[kq], acc2); \
            acc3 = MFMA32(aB, B##1[kq], acc3); } }

#define WAITR { asm volatile("s_waitcnt vmcnt(17)" ::: "memory"); \
                __builtin_amdgcn_sched_barrier(0); }

    f32x16 acc0 = {}, acc1 = {}, acc2 = {}, acc3 = {};
    const short* wp = (const short*)wt + l31 * 16 + lhi * 8;
    bf16x8 Bc0[4], Bc1[4], Bn0[4], Bn1[4];

    // prologue: idx 0..2, stage A[0] -> buf0, B[0] -> Bc
    int g0  = invr[oL];
    int gS  = invr[(size_t)n_down + oL];
    int gS2 = invr[2 * (size_t)n_down + oL];
    STAGE(0, g0);
    LDB(Bc, 0);

    // main loop: 80 regions (k = 0..79), unrolled x2 for named B/buf; k=80 epilogue
    for (int k = 0; k < 80; k += 2) {
        int t1, t2;
        // region k (even): stage A[k+1]->buf1, compute buf0 with Bc
        STAGE(1, gS);
        t1 = invr[(size_t)(k + 3) * n_down + oL];
        LDB(Bn, k + 1);
        WAITR;
        COMPUTE(0, Bc);
        // region k+1 (odd): stage A[k+2]->buf0, compute buf1 with Bn
        STAGE(0, gS2);
        t2 = invr[(size_t)(k + 4) * n_down + oL];   // k=78/79 read into invd rows (valid mem, unused)
        LDB(Bc, k + 2);
        WAITR;
        COMPUTE(1, Bn);
        gS = t1; gS2 = t2;
    }
    // k = 80: nothing left to stage/prefetch
    asm volatile("s_waitcnt vmcnt(0)" ::: "memory");
    __builtin_amdgcn_sched_barrier(0);
    COMPUTE(0, Bc);

    // epilogue: BN + ReLU, f32 out
#pragma unroll
    for (int m = 0; m < 2; ++m)
#pragma unroll
        for (int n = 0; n < 2; ++n) {
            int col = n * 32 + l31;
            float iv = gamma[col] * rsqrtf(var[col] + EPS_BN);
            float bb = beta[col] - mean[col] * iv;
            const f32x16& A = m == 0 ? (n == 0 ? acc0 : acc1) : (n == 0 ? acc2 : acc3);
#pragma unroll
            for (int i = 0; i < 16; ++i) {
                long oo = o0 + m * 32 + (i & 3) + 8 * (i >> 2) + 4 * lhi;
                if (oo < n_down)
                    out[oo * 64 + col] = fmaxf(A[i] * iv + bb, 0.f);
            }
        }
#undef STAGE
#undef LDB
#undef COMPUTE
#undef WAITR
}

extern "C" void kernel_launch(void* const* d_in, const int* in_sizes, int n_args,
                              void* d_out, int out_size, void* d_ws, size_t ws_size,
                              hipStream_t stream) {
    const float* feat    = (const float*)d_in[0];
    const float* w_down  = (const float*)d_in[1];
    const float* gamma_d = (const float*)d_in[2];
    const float* beta_d  = (const float*)d_in[3];
    const float* mean_d  = (const float*)d_in[4];
    const float* var_d   = (const float*)d_in[5];
    const float* w_ref   = (const float*)d_in[6];
    const float* gamma_r = (const float*)d_in[7];
    const float* beta_r  = (const float*)d_in[8];
    const float* mean_r  = (const float*)d_in[9];
    const float* var_r   = (const float*)d_in[10];
    const int*   gather_d  = (const int*)d_in[11];
    const int*   scatter_d = (const int*)d_in[12];
    const int*   gather_r  = (const int*)d_in[13];
    const int*   scatter_r = (const int*)d_in[14];

    int n_in   = in_sizes[0] / 32;
    int md     = in_sizes[11] / 16;
    int mr     = in_sizes[13] / 81;
    int n_down = out_size / 64;

    // ws: ybf[(n_down+1)*64]bf16 | featbf[(n_in+1)*32]bf16 | wt[81*4096]bf16 |
    //     wtd[16*2048]bf16 | invr[81*n_down]i32 | invd[16*n_down]i32 (contig for memset)
    char* ws = (char*)d_ws;
    size_t off = 0;
    auto alloc = [&](size_t bytes) { char* p = ws + off; off = (off + bytes + 255) & ~(size_t)255; return p; };
    unsigned short* ybf    = (unsigned short*)alloc((size_t)(n_down + 1) * 64 * 2);
    unsigned short* featbf = (unsigned short*)alloc((size_t)(n_in + 1) * 32 * 2);
    unsigned short* wt     = (unsigned short*)alloc((size_t)81 * 4096 * 2);
    unsigned short* wtd    = (unsigned short*)alloc((size_t)16 * 2048 * 2);
    int* invr = (int*)(ws + off);
    int* invd = invr + (size_t)81 * n_down;

    hipMemsetAsync(invr, 0xFF, (size_t)97 * n_down * sizeof(int), stream);

    long td = 16L * md;
    build_inv<<<(int)((td + 255) / 256), 256, 0, stream>>>(gather_d, scatter_d, td, md, invd, n_down);
    long tr = 81L * mr;
    build_inv<<<(int)((tr + 255) / 256), 256, 0, stream>>>(gather_r, scatter_r, tr, mr, invr, n_down);

    long ft = ((long)n_in * 32 + 32) / 4;
    fcvt<<<(int)((ft + 255) / 256), 256, 0, stream>>>(feat, featbf, ybf + (size_t)n_down * 64, n_in);
    wcvt_r<<<81 * 4096 / 256, 256, 0, stream>>>(w_ref, wt);
    wcvt_d<<<16 * 2048 / 256, 256, 0, stream>>>(w_down, wtd);

    long wavesD  = ((long)n_down + 31) / 32;
    int  blocksD = (int)((wavesD * 64 + 255) / 256);
    conv_down_mfma<<<blocksD, 256, 0, stream>>>(featbf, wtd, invd,
                                                gamma_d, beta_d, mean_d, var_d,
                                                ybf, n_down, n_in);

    long wavesR  = ((long)n_down + 63) / 64;
    int  blocksR = (int)((wavesR + 3) / 4);
    conv_ref_mfma<<<blocksR, 256, 0, stream>>>(ybf, wt, invr,
                                               gamma_r, beta_r, mean_r, var_r,
                                               (float*)d_out, n_down, blocksR);
}